// Round 4
// baseline (218.133 us; speedup 1.0000x reference)
//
#include <hip/hip_runtime.h>
#include <hip/hip_bf16.h>
#include <cmath>

// ---- model dims ----
#define F_   32
#define V_   1000
#define D_   64
#define B_   8192
#define IN_RAW  2544      // F*D + F*(F-1)/2 = 2048 + 496
#define IN_PAD  2560
#define H1_  1024
#define H2_  512
#define OUT_RAW 1000
#define OUT_PAD 1024

typedef __attribute__((ext_vector_type(4))) float f32x4;
typedef __attribute__((ext_vector_type(8))) __bf16 bf16x8;

typedef const __attribute__((address_space(1))) void* gptr_t;
typedef __attribute__((address_space(3))) void* lptr_t;

__device__ __forceinline__ void gload_lds16(const void* g, void* l) {
  __builtin_amdgcn_global_load_lds((gptr_t)g, (lptr_t)l, 16, 0, 0);
}

#define MF(a, b, c) __builtin_amdgcn_mfma_f32_16x16x32_bf16((a), (b), (c), 0, 0, 0)
#define SBAR asm volatile("s_barrier" ::: "memory")
#define WAITV(n) asm volatile("s_waitcnt vmcnt(" #n ")" ::: "memory")

// ---------------------------------------------------------------------------
// prep kernel: 3 weight transposes + embedding gather/interaction (round-3)
// ---------------------------------------------------------------------------
__global__ __launch_bounds__(256)
void prep_kernel(const int* __restrict__ x, const float* __restrict__ emb,
                 const float* __restrict__ W1, const float* __restrict__ W2,
                 const float* __restrict__ W3,
                 __hip_bfloat16* __restrict__ h, __hip_bfloat16* __restrict__ w1t,
                 __hip_bfloat16* __restrict__ w2t, __hip_bfloat16* __restrict__ w3t)
{
  __shared__ __align__(16) char smem[16384];
  const int bid = blockIdx.x;
  const int tid = threadIdx.x;

  if (bid < 3584) {
    const float* W; __hip_bfloat16* Wt; int K, N, Kpad, kb, nb;
    if (bid < 2560)      { W = W1; Wt = w1t; K = IN_RAW; N = H1_;     Kpad = IN_PAD; kb = bid % 80; nb = bid / 80; }
    else if (bid < 3072) { int r = bid - 2560; W = W2; Wt = w2t; K = H1_; N = H2_;   Kpad = H1_;   kb = r % 32;  nb = r / 32; }
    else                 { int r = bid - 3072; W = W3; Wt = w3t; K = H2_; N = OUT_RAW; Kpad = H2_; kb = r % 16;  nb = r / 16; }
    float (*t)[33] = (float(*)[33])smem;
    const int k0 = kb * 32, n0 = nb * 32;
    const int tx = tid & 31, ty = tid >> 5;
#pragma unroll
    for (int i = 0; i < 4; ++i) {
      int r = ty + i * 8;
      int k = k0 + r, n = n0 + tx;
      t[r][tx] = (k < K && n < N) ? W[(size_t)k * N + n] : 0.f;
    }
    __syncthreads();
#pragma unroll
    for (int i = 0; i < 4; ++i) {
      int r = ty + i * 8;
      Wt[(size_t)(n0 + r) * Kpad + (k0 + tx)] = __float2bfloat16(t[tx][r]);
    }
  } else {
    __hip_bfloat16 (*e4)[2048] = (__hip_bfloat16(*)[2048])smem;   // [4][32*64]
    const int wid  = tid >> 6;
    const int lane = tid & 63;
    const int b = (bid - 3584) * 4 + wid;
    const int* xb = x + b * F_;
    const size_t hrow = (size_t)b * IN_PAD;

#pragma unroll
    for (int it = 0; it < 8; ++it) {
      const int r = it * 4 + (lane >> 4);
      const int d = (lane & 15) * 4;
      const int idx = xb[r];
      const float4 v = *reinterpret_cast<const float4*>(
          &emb[((size_t)r * V_ + idx) * D_ + d]);
      __hip_bfloat16 tb[4];
      tb[0] = __float2bfloat16(v.x); tb[1] = __float2bfloat16(v.y);
      tb[2] = __float2bfloat16(v.z); tb[3] = __float2bfloat16(v.w);
      const ushort4 pk = *reinterpret_cast<const ushort4*>(tb);
      *reinterpret_cast<ushort4*>(&h[hrow + r * 64 + d]) = pk;
      const int ch = (d >> 3) ^ (r & 7);
      *reinterpret_cast<ushort4*>(&e4[wid][r * 64 + ch * 8 + (d & 7)]) = pk;
    }
    __syncthreads();

    f32x4 g[2][2] = {};
#pragma unroll
    for (int kk = 0; kk < 2; ++kk) {
      bf16x8 fa[2];
#pragma unroll
      for (int t2 = 0; t2 < 2; ++t2) {
        const int r = t2 * 16 + (lane & 15);
        const int ch = (kk * 4 + (lane >> 4)) ^ (r & 7);
        fa[t2] = *reinterpret_cast<const bf16x8*>(&e4[wid][r * 64 + ch * 8]);
      }
#pragma unroll
      for (int ti = 0; ti < 2; ++ti)
#pragma unroll
        for (int tj = 0; tj < 2; ++tj)
          g[ti][tj] = MF(fa[ti], fa[tj], g[ti][tj]);
    }

#pragma unroll
    for (int ti = 0; ti < 2; ++ti)
#pragma unroll
      for (int tj = 0; tj < 2; ++tj) {
        const int jj = tj * 16 + (lane & 15);
#pragma unroll
        for (int q = 0; q < 4; ++q) {
          const int i = ti * 16 + (lane >> 4) * 4 + q;
          if (i < jj) {
            const int p = i * 31 - (i * (i - 1)) / 2 + (jj - i - 1);
            h[hrow + 2048 + p] = __float2bfloat16(g[ti][tj][q]);
          }
        }
      }
    if (lane < IN_PAD - IN_RAW) h[hrow + IN_RAW + lane] = __float2bfloat16(0.f);
  }
}

// ---------------------------------------------------------------------------
// gemm_body: C = A[M][K] * Bt[N][K]^T. 128x128 tile, BK=32, 4 LDS buffers,
// depth-3 prefetch: iter t stages tile t+3, computes tile t, then waits
// vmcnt(8) (retires tile t+1's loads, issued 2+ iters ago) + raw s_barrier.
// No __syncthreads in the loop (would drain vmcnt). Stripe-XOR swizzle:
// 8-slot index within each 128B 2-row stripe, pslot = ((r&1)*4+c)^((r>>1)&7);
// applied as inverse-swizzled GLOBAL source (gload_lds writes linearly) +
// swizzled ds_read address (both-sides-or-neither, rule 21).
// ---------------------------------------------------------------------------
template <int EPI>
__device__ __forceinline__ void gemm_body(
    const __hip_bfloat16* __restrict__ A,
    const __hip_bfloat16* __restrict__ Bt,
    const float* __restrict__ bias,
    void* __restrict__ Cout,
    int M, int N, int K, int Nreal)
{
  __shared__ __align__(16) char lds[4][32768];   // [buf][A 16KB | B 16KB] = 64 KB

  const int tid  = threadIdx.x;
  const int wid  = tid >> 6;
  const int lane = tid & 63;
  const int wr = wid >> 1, wc = wid & 1;         // 2x2 waves -> 64x64 each
  const int lr = lane & 15;
  const int lhi = lane >> 4;                     // k-chunk 0..3
  const long rowBase = (long)blockIdx.x * 128;
  const long colBase = (long)blockIdx.y * 128;

  f32x4 acc[4][4] = {};

  // stage-side inverse swizzle: physical slot P = issue*256 + tid
  //   prow = P>>2 (row within 64-row issue), pch = P&3 (16B chunk in 64B row)
  //   stripe = prow>>1; pslot = (prow&1)*4 + pch; lslot = pslot ^ (stripe&7)
  //   logical row = stripe*2 + (lslot>>2); logical k-chunk = lslot&3
  const int prow  = tid >> 2;
  const int pch   = tid & 3;
  const int s7    = (prow >> 1) & 7;
  const int lslot = (((prow & 1) << 2) | pch) ^ s7;
  const int lrow  = ((prow >> 1) << 1) | (lslot >> 2);
  const int lch8  = (lslot & 3) << 3;
  const __hip_bfloat16* A0 = A  + (rowBase + lrow) * (long)K + lch8;
  const __hip_bfloat16* A1 = A  + (rowBase + 64 + lrow) * (long)K + lch8;
  const __hip_bfloat16* B0 = Bt + (colBase + lrow) * (long)K + lch8;
  const __hip_bfloat16* B1 = Bt + (colBase + 64 + lrow) * (long)K + lch8;
  char* const ldsw = &lds[0][0] + wid * 1024;    // wave-uniform LDS dest base

  const int NT = K >> 5;   // always >= 16 here

  auto STAGE = [&](int buf, int t) {
    const long k0 = (long)t << 5;
    char* lb = ldsw + buf * 32768;
    gload_lds16(A0 + k0, lb);                    // A rows 0-63
    gload_lds16(A1 + k0, lb + 4096);             // A rows 64-127
    gload_lds16(B0 + k0, lb + 16384);            // B rows 0-63
    gload_lds16(B1 + k0, lb + 20480);            // B rows 64-127
  };

  // swizzled read offset (bytes) for logical (row r, k-chunk c)
  auto loff = [&](int r, int c) -> int {
    return ((r >> 1) << 7) + (((((r & 1) << 2) | c) ^ ((r >> 1) & 7)) << 4);
  };

  auto COMPUTE = [&](int buf) {
    const char* ba = &lds[0][0] + buf * 32768;
    const char* bb = ba + 16384;
    bf16x8 af[4], bv[4];
#pragma unroll
    for (int m = 0; m < 4; ++m)
      af[m] = *reinterpret_cast<const bf16x8*>(ba + loff(wr * 64 + m * 16 + lr, lhi));
#pragma unroll
    for (int n = 0; n < 4; ++n)
      bv[n] = *reinterpret_cast<const bf16x8*>(bb + loff(wc * 64 + n * 16 + lr, lhi));
#pragma unroll
    for (int m = 0; m < 4; ++m)
#pragma unroll
      for (int n = 0; n < 4; ++n)
        acc[m][n] = MF(af[m], bv[n], acc[m][n]);
  };

  // prologue: fill 3 tiles; wait tile 0 (leave tiles 1,2 = 8 loads in flight)
  STAGE(0, 0); STAGE(1, 1); STAGE(2, 2);
  WAITV(8); SBAR;

  for (int t = 0; t < NT; ++t) {
    if (t + 3 < NT) STAGE((t + 3) & 3, t + 3);
    COMPUTE(t & 3);
    if (t + 3 < NT)      { WAITV(8); SBAR; }   // retire tile t+1 (issued iter t-2)
    else if (t + 2 < NT) { WAITV(4); SBAR; }
    else if (t + 1 < NT) { WAITV(0); SBAR; }
  }

  // epilogue: C/D layout col = lane&15, row = (lane>>4)*4 + reg
#pragma unroll
  for (int m = 0; m < 4; ++m) {
    const long row0 = rowBase + wr * 64 + m * 16 + lhi * 4;
#pragma unroll
    for (int n = 0; n < 4; ++n) {
      const int col = (int)colBase + wc * 64 + n * 16 + lr;
      const float bvs = (col < Nreal) ? bias[col] : 0.f;
#pragma unroll
      for (int j = 0; j < 4; ++j) {
        float v = acc[m][n][j] + bvs;
        const long row = row0 + j;
        if (EPI == 0) {
          ((__hip_bfloat16*)Cout)[row * N + col] = __float2bfloat16(fmaxf(v, 0.f));
        } else {
          if (col < Nreal)
            ((float*)Cout)[row * Nreal + col] = 1.f / (1.f + expf(-v));
        }
      }
    }
  }
}

// distinct names so rocprof top-5 shows the per-layer breakdown
__global__ __launch_bounds__(256)
void gemm_L1(const __hip_bfloat16* A, const __hip_bfloat16* Bt, const float* bias,
             void* C, int M, int N, int K, int Nreal) {
  gemm_body<0>(A, Bt, bias, C, M, N, K, Nreal);
}
__global__ __launch_bounds__(256)
void gemm_L2(const __hip_bfloat16* A, const __hip_bfloat16* Bt, const float* bias,
             void* C, int M, int N, int K, int Nreal) {
  gemm_body<0>(A, Bt, bias, C, M, N, K, Nreal);
}
__global__ __launch_bounds__(256)
void gemm_L3(const __hip_bfloat16* A, const __hip_bfloat16* Bt, const float* bias,
             void* C, int M, int N, int K, int Nreal) {
  gemm_body<1>(A, Bt, bias, C, M, N, K, Nreal);
}

// ---------------------------------------------------------------------------
extern "C" void kernel_launch(void* const* d_in, const int* in_sizes, int n_in,
                              void* d_out, int out_size, void* d_ws, size_t ws_size,
                              hipStream_t stream)
{
  const int*   x   = (const int*)  d_in[0];
  const float* emb = (const float*)d_in[1];
  const float* W1  = (const float*)d_in[2];
  const float* b1  = (const float*)d_in[3];
  const float* W2  = (const float*)d_in[4];
  const float* b2  = (const float*)d_in[5];
  const float* W3  = (const float*)d_in[6];
  const float* b3  = (const float*)d_in[7];
  float* out = (float*)d_out;

  char* ws = (char*)d_ws;
  size_t off = 0;
  auto alloc = [&](size_t bytes) { size_t o = off; off = (off + bytes + 255) & ~255ULL; return o; };
  __hip_bfloat16* h   = (__hip_bfloat16*)(ws + alloc((size_t)B_ * IN_PAD * 2));
  __hip_bfloat16* w1t = (__hip_bfloat16*)(ws + alloc((size_t)H1_ * IN_PAD * 2));
  __hip_bfloat16* w2t = (__hip_bfloat16*)(ws + alloc((size_t)H2_ * H1_ * 2));
  __hip_bfloat16* w3t = (__hip_bfloat16*)(ws + alloc((size_t)OUT_PAD * H2_ * 2));
  __hip_bfloat16* h1  = (__hip_bfloat16*)(ws + alloc((size_t)B_ * H1_ * 2));
  __hip_bfloat16* h2  = (__hip_bfloat16*)(ws + alloc((size_t)B_ * H2_ * 2));

  prep_kernel<<<5632, 256, 0, stream>>>(x, emb, W1, W2, W3, h, w1t, w2t, w3t);

  // L1: h[8192][2560] @ W1 -> h1 bf16 [8192][1024], relu   (512 blocks, 2/CU)
  gemm_L1<<<dim3(B_ / 128, H1_ / 128), 256, 0, stream>>>(h, w1t, b1, h1, B_, H1_, IN_PAD, H1_);
  // L2: h1 @ W2 -> h2 bf16 [8192][512], relu               (256 blocks)
  gemm_L2<<<dim3(B_ / 128, H2_ / 128), 256, 0, stream>>>(h1, w2t, b2, h2, B_, H2_, H1_, H2_);
  // L3: h2 @ W3 -> out fp32 [8192][1000], sigmoid          (512 blocks)
  gemm_L3<<<dim3(B_ / 128, OUT_PAD / 128), 256, 0, stream>>>(h2, w3t, b3, out, B_, OUT_PAD, H2_, OUT_RAW);
}

// Round 6
// 182.818 us; speedup vs baseline: 1.1932x; 1.1932x over previous
//
#include <hip/hip_runtime.h>
#include <hip/hip_bf16.h>
#include <cmath>

// ---- model dims ----
#define F_   32
#define V_   1000
#define D_   64
#define B_   8192
#define IN_RAW  2544      // F*D + F*(F-1)/2 = 2048 + 496
#define IN_PAD  2560
#define H1_  1024
#define H2_  512
#define OUT_RAW 1000
#define OUT_PAD 1024

typedef __attribute__((ext_vector_type(4))) float f32x4;
typedef __attribute__((ext_vector_type(8))) __bf16 bf16x8;

typedef const __attribute__((address_space(1))) void* gptr_t;
typedef __attribute__((address_space(3))) void* lptr_t;

__device__ __forceinline__ void gload_lds16(const void* g, void* l) {
  __builtin_amdgcn_global_load_lds((gptr_t)g, (lptr_t)l, 16, 0, 0);
}

#define MF(a, b, c) __builtin_amdgcn_mfma_f32_16x16x32_bf16((a), (b), (c), 0, 0, 0)

// ---------------------------------------------------------------------------
// prep kernel: 3 weight transposes + embedding gather/interaction (proven)
// ---------------------------------------------------------------------------
__global__ __launch_bounds__(256)
void prep_kernel(const int* __restrict__ x, const float* __restrict__ emb,
                 const float* __restrict__ W1, const float* __restrict__ W2,
                 const float* __restrict__ W3,
                 __hip_bfloat16* __restrict__ h, __hip_bfloat16* __restrict__ w1t,
                 __hip_bfloat16* __restrict__ w2t, __hip_bfloat16* __restrict__ w3t)
{
  __shared__ __align__(16) char smem[16384];
  const int bid = blockIdx.x;
  const int tid = threadIdx.x;

  if (bid < 3584) {
    const float* W; __hip_bfloat16* Wt; int K, N, Kpad, kb, nb;
    if (bid < 2560)      { W = W1; Wt = w1t; K = IN_RAW; N = H1_;     Kpad = IN_PAD; kb = bid % 80; nb = bid / 80; }
    else if (bid < 3072) { int r = bid - 2560; W = W2; Wt = w2t; K = H1_; N = H2_;   Kpad = H1_;   kb = r % 32;  nb = r / 32; }
    else                 { int r = bid - 3072; W = W3; Wt = w3t; K = H2_; N = OUT_RAW; Kpad = H2_; kb = r % 16;  nb = r / 16; }
    float (*t)[33] = (float(*)[33])smem;
    const int k0 = kb * 32, n0 = nb * 32;
    const int tx = tid & 31, ty = tid >> 5;
#pragma unroll
    for (int i = 0; i < 4; ++i) {
      int r = ty + i * 8;
      int k = k0 + r, n = n0 + tx;
      t[r][tx] = (k < K && n < N) ? W[(size_t)k * N + n] : 0.f;
    }
    __syncthreads();
#pragma unroll
    for (int i = 0; i < 4; ++i) {
      int r = ty + i * 8;
      Wt[(size_t)(n0 + r) * Kpad + (k0 + tx)] = __float2bfloat16(t[tx][r]);
    }
  } else {
    __hip_bfloat16 (*e4)[2048] = (__hip_bfloat16(*)[2048])smem;   // [4][32*64]
    const int wid  = tid >> 6;
    const int lane = tid & 63;
    const int b = (bid - 3584) * 4 + wid;
    const int* xb = x + b * F_;
    const size_t hrow = (size_t)b * IN_PAD;

#pragma unroll
    for (int it = 0; it < 8; ++it) {
      const int r = it * 4 + (lane >> 4);
      const int d = (lane & 15) * 4;
      const int idx = xb[r];
      const float4 v = *reinterpret_cast<const float4*>(
          &emb[((size_t)r * V_ + idx) * D_ + d]);
      __hip_bfloat16 tb[4];
      tb[0] = __float2bfloat16(v.x); tb[1] = __float2bfloat16(v.y);
      tb[2] = __float2bfloat16(v.z); tb[3] = __float2bfloat16(v.w);
      const ushort4 pk = *reinterpret_cast<const ushort4*>(tb);
      *reinterpret_cast<ushort4*>(&h[hrow + r * 64 + d]) = pk;
      const int ch = (d >> 3) ^ (r & 7);
      *reinterpret_cast<ushort4*>(&e4[wid][r * 64 + ch * 8 + (d & 7)]) = pk;
    }
    __syncthreads();

    f32x4 g[2][2] = {};
#pragma unroll
    for (int kk = 0; kk < 2; ++kk) {
      bf16x8 fa[2];
#pragma unroll
      for (int t2 = 0; t2 < 2; ++t2) {
        const int r = t2 * 16 + (lane & 15);
        const int ch = (kk * 4 + (lane >> 4)) ^ (r & 7);
        fa[t2] = *reinterpret_cast<const bf16x8*>(&e4[wid][r * 64 + ch * 8]);
      }
#pragma unroll
      for (int ti = 0; ti < 2; ++ti)
#pragma unroll
        for (int tj = 0; tj < 2; ++tj)
          g[ti][tj] = MF(fa[ti], fa[tj], g[ti][tj]);
    }

#pragma unroll
    for (int ti = 0; ti < 2; ++ti)
#pragma unroll
      for (int tj = 0; tj < 2; ++tj) {
        const int jj = tj * 16 + (lane & 15);
#pragma unroll
        for (int q = 0; q < 4; ++q) {
          const int i = ti * 16 + (lane >> 4) * 4 + q;
          if (i < jj) {
            const int p = i * 31 - (i * (i - 1)) / 2 + (jj - i - 1);
            h[hrow + 2048 + p] = __float2bfloat16(g[ti][tj][q]);
          }
        }
      }
    if (lane < IN_PAD - IN_RAW) h[hrow + IN_RAW + lane] = __float2bfloat16(0.f);
  }
}

// ---------------------------------------------------------------------------
// gemm_body: C = A[M][K] * Bt[N][K]^T. Round-2 proven 2-phase structure:
// BK=64, double-buffered LDS, prefetch-before-compute, XOR-swizzled LDS
// (pre-swizzled global source + swizzled ds_read; conflicts measured = 0).
// NW = per-wave N fragments: NW=4 -> 128x128 tile (32KB/buf), NW=2 ->
// 128x64 tile (24KB/buf, 512 blocks for N=512 -> 2 blocks/CU).
// Flattened 1-D grid with bijective XCD swizzle: 8 consecutive swizzled
// blocks share one A-panel per XCD (nCol == 8 for all layers here).
// ---------------------------------------------------------------------------
template <int EPI, int NW>
__device__ __forceinline__ void gemm_body(
    const __hip_bfloat16* __restrict__ A,
    const __hip_bfloat16* __restrict__ Bt,
    const float* __restrict__ bias,
    void* __restrict__ Cout,
    int M, int N, int K, int Nreal)
{
  constexpr int BN = NW * 32;                    // B-tile rows
  constexpr int ABYTES = 128 * 64 * 2;           // 16 KB
  constexpr int BBYTES = BN * 64 * 2;            // 16 or 8 KB
  constexpr int BUFB = ABYTES + BBYTES;
  __shared__ __align__(16) char lds[2][BUFB];

  const int tid  = threadIdx.x;
  const int wid  = tid >> 6;
  const int lane = tid & 63;
  const int wr = wid >> 1, wc = wid & 1;
  const int lr = lane & 15;
  const int lhi = lane >> 4;

  // XCD bijective swizzle (nwg % 8 == 0 for all layers)
  const int nCol = N / BN;
  const int nwg  = gridDim.x;
  const int bid  = blockIdx.x;
  const int swz  = (bid & 7) * (nwg >> 3) + (bid >> 3);
  const long rowBase = (long)(swz / nCol) * 128;
  const long colBase = (long)(swz % nCol) * BN;

  f32x4 acc[4][NW] = {};

  const int srow = tid >> 3;                     // 0..31 (row within 32-row issue)
  const long scol = (long)(((tid & 7) ^ (srow & 7)) * 8);   // pre-swizzled source
  const long aBase = (rowBase + srow) * (long)K + scol;
  const long bBase = (colBase + srow) * (long)K + scol;

  const int NT = K >> 6;

  auto STAGE = [&](int buf, int t) {
    const long k0 = (long)t * 64;
    char* la = &lds[buf][0] + wid * 1024;
    char* lb = &lds[buf][ABYTES] + wid * 1024;
#pragma unroll
    for (int j = 0; j < 4; ++j)
      gload_lds16(A + aBase + (long)j * 32 * K + k0, la + j * 4096);
#pragma unroll
    for (int j = 0; j < BN / 32; ++j)
      gload_lds16(Bt + bBase + (long)j * 32 * K + k0, lb + j * 4096);
  };

  STAGE(0, 0);
  __syncthreads();

  int cur = 0;
  for (int t = 0; t < NT; ++t) {
    if (t + 1 < NT) STAGE(cur ^ 1, t + 1);

    const __hip_bfloat16* la = (const __hip_bfloat16*)&lds[cur][0];
    const __hip_bfloat16* lb = (const __hip_bfloat16*)&lds[cur][ABYTES];
#pragma unroll
    for (int kk = 0; kk < 2; ++kk) {
      const int ch = ((kk * 4 + lhi) ^ (lane & 7)) * 8;
      bf16x8 af[4], bfv[NW];
#pragma unroll
      for (int m = 0; m < 4; ++m)
        af[m] = *reinterpret_cast<const bf16x8*>(&la[(wr * 64 + m * 16 + lr) * 64 + ch]);
#pragma unroll
      for (int n = 0; n < NW; ++n)
        bfv[n] = *reinterpret_cast<const bf16x8*>(&lb[(wc * (BN / 2) + n * 16 + lr) * 64 + ch]);
#pragma unroll
      for (int m = 0; m < 4; ++m)
#pragma unroll
        for (int n = 0; n < NW; ++n)
          acc[m][n] = MF(af[m], bfv[n], acc[m][n]);
    }
    __syncthreads();
    cur ^= 1;
  }

  // epilogue: C/D layout col = lane&15, row = (lane>>4)*4 + reg
#pragma unroll
  for (int m = 0; m < 4; ++m) {
    const long row0 = rowBase + wr * 64 + m * 16 + lhi * 4;
#pragma unroll
    for (int n = 0; n < NW; ++n) {
      const int col = (int)colBase + wc * (BN / 2) + n * 16 + lr;
      const float bv = (col < Nreal) ? bias[col] : 0.f;
#pragma unroll
      for (int j = 0; j < 4; ++j) {
        float v = acc[m][n][j] + bv;
        const long row = row0 + j;
        if (EPI == 0) {
          ((__hip_bfloat16*)Cout)[row * N + col] = __float2bfloat16(fmaxf(v, 0.f));
        } else {
          if (col < Nreal)
            ((float*)Cout)[row * Nreal + col] = 1.f / (1.f + __expf(-v));
        }
      }
    }
  }
}

// distinct names so the profile reveals the true per-layer breakdown
__global__ __launch_bounds__(256)
void gemm_L1(const __hip_bfloat16* A, const __hip_bfloat16* Bt, const float* bias,
             void* C, int M, int N, int K, int Nreal) {
  gemm_body<0, 4>(A, Bt, bias, C, M, N, K, Nreal);
}
__global__ __launch_bounds__(256)
void gemm_L2(const __hip_bfloat16* A, const __hip_bfloat16* Bt, const float* bias,
             void* C, int M, int N, int K, int Nreal) {
  gemm_body<0, 2>(A, Bt, bias, C, M, N, K, Nreal);
}
__global__ __launch_bounds__(256)
void gemm_L3(const __hip_bfloat16* A, const __hip_bfloat16* Bt, const float* bias,
             void* C, int M, int N, int K, int Nreal) {
  gemm_body<1, 4>(A, Bt, bias, C, M, N, K, Nreal);
}

// ---------------------------------------------------------------------------
extern "C" void kernel_launch(void* const* d_in, const int* in_sizes, int n_in,
                              void* d_out, int out_size, void* d_ws, size_t ws_size,
                              hipStream_t stream)
{
  const int*   x   = (const int*)  d_in[0];
  const float* emb = (const float*)d_in[1];
  const float* W1  = (const float*)d_in[2];
  const float* b1  = (const float*)d_in[3];
  const float* W2  = (const float*)d_in[4];
  const float* b2  = (const float*)d_in[5];
  const float* W3  = (const float*)d_in[6];
  const float* b3  = (const float*)d_in[7];
  float* out = (float*)d_out;

  char* ws = (char*)d_ws;
  size_t off = 0;
  auto alloc = [&](size_t bytes) { size_t o = off; off = (off + bytes + 255) & ~255ULL; return o; };
  __hip_bfloat16* h   = (__hip_bfloat16*)(ws + alloc((size_t)B_ * IN_PAD * 2));
  __hip_bfloat16* w1t = (__hip_bfloat16*)(ws + alloc((size_t)H1_ * IN_PAD * 2));
  __hip_bfloat16* w2t = (__hip_bfloat16*)(ws + alloc((size_t)H2_ * H1_ * 2));
  __hip_bfloat16* w3t = (__hip_bfloat16*)(ws + alloc((size_t)OUT_PAD * H2_ * 2));
  __hip_bfloat16* h1  = (__hip_bfloat16*)(ws + alloc((size_t)B_ * H1_ * 2));
  __hip_bfloat16* h2  = (__hip_bfloat16*)(ws + alloc((size_t)B_ * H2_ * 2));

  prep_kernel<<<5632, 256, 0, stream>>>(x, emb, W1, W2, W3, h, w1t, w2t, w3t);

  // L1: h[8192][2560] @ W1 -> h1 bf16 [8192][1024], relu   (512 blocks, 2/CU)
  gemm_L1<<<(B_ / 128) * (H1_ / 128), 256, 0, stream>>>(h, w1t, b1, h1, B_, H1_, IN_PAD, H1_);
  // L2: h1 @ W2 -> h2 bf16 [8192][512], relu               (512 blocks, 2/CU)
  gemm_L2<<<(B_ / 128) * (H2_ / 64), 256, 0, stream>>>(h1, w2t, b2, h2, B_, H2_, H1_, H2_);
  // L3: h2 @ W3 -> out fp32 [8192][1000], sigmoid          (512 blocks, 2/CU)
  gemm_L3<<<(B_ / 128) * (OUT_PAD / 128), 256, 0, stream>>>(h2, w3t, b3, out, B_, OUT_PAD, H2_, OUT_RAW);
}